// Round 10
// baseline (114.709 us; speedup 1.0000x reference)
//
#include <hip/hip_runtime.h>

#define NDOM 8
#define TT   64      // tile dim (64x64 upper-triangle tiles)
#define KDIM 1024    // feature dim (harness-fixed)
#define RPAD 1040    // LDS row stride: 1024 + 16 pad -> 4-bank skew per row
#define BMAX 4096    // batch (harness-fixed)
#define GGRID 512    // k_gram grid

typedef float f32x4 __attribute__((ext_vector_type(4)));

__device__ inline void gload16(const void* g, void* l) {
    __builtin_amdgcn_global_load_lds(
        (const __attribute__((address_space(1))) unsigned int*)g,
        (__attribute__((address_space(3))) unsigned int*)l, 16, 0, 0);
}

// ------------------------------------------------------------------ prep ----
// Block 0: label bucketing (ballot/popc) -> perm, dom_off.
// Blocks 1..: fp32 -> fp8(e4m3) convert in ORIGINAL order (16 rows/block).
__global__ __launch_bounds__(256) void k_prep(
    const float* __restrict__ F, const int* __restrict__ labels, int B,
    unsigned char* __restrict__ Fb, float* __restrict__ sq,
    int* __restrict__ perm, int* __restrict__ dom_off) {
    const int t = threadIdx.x, lane = t & 63, wv = t >> 6;

    if (blockIdx.x == 0) {
        __shared__ int lab[BMAX];
        __shared__ unsigned wcnt[4][NDOM];
        for (int i = t; i < BMAX; i += 256) lab[i] = (i < B) ? labels[i] : -1;
        __syncthreads();

        int nch = (B + 63) >> 6;
        int cpw = (nch + 3) >> 2;
        int c0 = wv * cpw, c1 = min(c0 + cpw, nch);
        unsigned long long below = (1ull << lane) - 1ull;

        unsigned cnt[NDOM];
#pragma unroll
        for (int d = 0; d < NDOM; ++d) cnt[d] = 0;
        for (int c = c0; c < c1; ++c) {
            int d = lab[c * 64 + lane];
#pragma unroll
            for (int dd = 0; dd < NDOM; ++dd)
                cnt[dd] += (unsigned)__popcll(__ballot(d == dd));
        }
        if (lane == 0)
#pragma unroll
            for (int dd = 0; dd < NDOM; ++dd) wcnt[wv][dd] = cnt[dd];
        __syncthreads();

        unsigned offs[NDOM + 1];
        offs[0] = 0;
#pragma unroll
        for (int dd = 0; dd < NDOM; ++dd)
            offs[dd + 1] = offs[dd] + wcnt[0][dd] + wcnt[1][dd] + wcnt[2][dd] + wcnt[3][dd];
        if (t <= NDOM) dom_off[t] = (int)offs[t];

        unsigned run[NDOM];
#pragma unroll
        for (int dd = 0; dd < NDOM; ++dd) {
            unsigned base = offs[dd];
            for (int w = 0; w < 4; ++w)
                if (w < wv) base += wcnt[w][dd];
            run[dd] = base;
        }
        for (int c = c0; c < c1; ++c) {
            int i = c * 64 + lane;
            int d = lab[i];
            int pos = -1;
#pragma unroll
            for (int dd = 0; dd < NDOM; ++dd) {
                unsigned long long m = __ballot(d == dd);
                if (d == dd) pos = (int)run[dd] + __popcll(m & below);
                run[dd] += (unsigned)__popcll(m);
            }
            if (i < B) perm[pos] = i;
        }
        return;
    }

    int i0 = (int)(blockIdx.x - 1) * 16;
    for (int j = wv; j < 16; j += 4) {
        int row = i0 + j;
        if (row >= B) break;
        const float4* srow = (const float4*)(F + (size_t)row * KDIM);
        int* drow = (int*)(Fb + (size_t)row * KDIM);
        float ss = 0.f;
#pragma unroll
        for (int it = 0; it < 4; ++it) {
            float4 v = srow[it * 64 + lane];
            ss += v.x * v.x + v.y * v.y + v.z * v.z + v.w * v.w;
            int p = __builtin_amdgcn_cvt_pk_fp8_f32(v.x, v.y, 0, false);
            p = __builtin_amdgcn_cvt_pk_fp8_f32(v.z, v.w, p, true);
            drow[it * 64 + lane] = p;
        }
#pragma unroll
        for (int s = 32; s > 0; s >>= 1) ss += __shfl_xor(ss, s);
        if (lane == 0) sq[row] = ss;
    }
}

// ------------------------------------------------------------------ gram ----
// Identical to R9 (64x64 upper-triangle fp8 tiles, full-K LDS-resident,
// block-private partial export). Launched TWICE this round as a controlled
// cost probe: the kernel is idempotent (part fully overwritten each run).
__global__ __launch_bounds__(256) void k_gram(
    const unsigned char* __restrict__ Fb, const float* __restrict__ sq,
    const int* __restrict__ perm, const int* __restrict__ dom_off,
    float* __restrict__ part) {
    __shared__ __align__(16) unsigned char lA[TT * RPAD];  // 65 KB
    __shared__ __align__(16) unsigned char lB[TT * RPAD];  // 65 KB
    __shared__ int s_p[128];
    __shared__ float s_sq[128];
    __shared__ int s_offs[NDOM + 1], s_ts[NDOM + 1];
    __shared__ float s_ps[NDOM];

    const int t = threadIdx.x, lane = t & 63, wv = t >> 6;
    const int m16 = lane & 15, quad = lane >> 4;
    const int wm = (wv & 1) * 32, wn = (wv >> 1) * 32;

    if (t == 0) {
        int T = 0;
        for (int d = 0; d < NDOM; ++d) {
            int o0 = dom_off[d], o1 = dom_off[d + 1];
            s_offs[d] = o0;
            s_ts[d] = T;
            int n = o1 - o0;
            int nt = (n + TT - 1) / TT;
            T += nt * (nt + 1) / 2;
        }
        s_offs[NDOM] = dom_off[NDOM];
        s_ts[NDOM] = T;
    }
    if (t < NDOM) s_ps[t] = 0.f;
    __syncthreads();
    const int T = s_ts[NDOM];

    for (int tile = blockIdx.x; tile < T; tile += gridDim.x) {
        int dom = 0;
        while (tile >= s_ts[dom + 1]) ++dom;
        int off = s_offs[dom], n = s_offs[dom + 1] - off;
        int nt = (n + TT - 1) / TT;
        int rel = tile - s_ts[dom];
        int ty = 0, rem = rel;
        while (rem >= nt - ty) { rem -= nt - ty; ++ty; }
        int tx = ty + rem;
        int tr = ty * TT, tc = tx * TT;
        bool diag = (ty == tx);

        // rows at s_p[0..63], cols at s_p[64..127]
        if (t < 128) {
            int r = (t < 64) ? min(tr + t, n - 1) : min(tc + (t - 64), n - 1);
            int p = perm[off + r];
            s_p[t] = p;
            s_sq[t] = sq[p];
        }
        __syncthreads();

        // staging: 1 instr/row, lanes linear (coalesced 1 KB/instr)
#pragma unroll
        for (int j = 0; j < 16; ++j) {
            int r = wv * 16 + j;          // 0..63
            gload16(Fb + (size_t)s_p[r] * KDIM + lane * 16, lA + r * RPAD);
            if (!diag)
                gload16(Fb + (size_t)s_p[64 + r] * KDIM + lane * 16, lB + r * RPAD);
        }
        __syncthreads();   // single vmcnt drain per tile

        const unsigned char* Bb = diag ? lA : lB;
        const unsigned char* pa0 = lA + (wm + m16) * RPAD + quad * 8;
        const unsigned char* pa1 = lA + (wm + 16 + m16) * RPAD + quad * 8;
        const unsigned char* pb0 = Bb + (wn + m16) * RPAD + quad * 8;
        const unsigned char* pb1 = Bb + (wn + 16 + m16) * RPAD + quad * 8;
        f32x4 a00 = (f32x4){0.f, 0.f, 0.f, 0.f};
        f32x4 a01 = (f32x4){0.f, 0.f, 0.f, 0.f};
        f32x4 a10 = (f32x4){0.f, 0.f, 0.f, 0.f};
        f32x4 a11 = (f32x4){0.f, 0.f, 0.f, 0.f};
#pragma unroll
        for (int ks = 0; ks < 32; ++ks) {
            long av0 = *(const long*)(pa0 + ks * 32);
            long av1 = *(const long*)(pa1 + ks * 32);
            long bv0 = *(const long*)(pb0 + ks * 32);
            long bv1 = *(const long*)(pb1 + ks * 32);
            a00 = __builtin_amdgcn_mfma_f32_16x16x32_fp8_fp8(av0, bv0, a00, 0, 0, 0);
            a01 = __builtin_amdgcn_mfma_f32_16x16x32_fp8_fp8(av0, bv1, a01, 0, 0, 0);
            a10 = __builtin_amdgcn_mfma_f32_16x16x32_fp8_fp8(av1, bv0, a10, 0, 0, 0);
            a11 = __builtin_amdgcn_mfma_f32_16x16x32_fp8_fp8(av1, bv1, a11, 0, 0, 0);
        }

        // epilogue: subtile (im,in): C[row=quad*4+r][col=m16]
        float local = 0.f;
#pragma unroll
        for (int im = 0; im < 2; ++im) {
            int lr0 = wm + im * 16 + quad * 4;
#pragma unroll
            for (int in = 0; in < 2; ++in) {
                f32x4 av = (im == 0) ? ((in == 0) ? a00 : a01)
                                     : ((in == 0) ? a10 : a11);
                int lc = wn + in * 16 + m16;
                int pc = tc + lc;
                if (pc >= n) continue;
                float sb = s_sq[64 + lc];
#pragma unroll
                for (int r = 0; r < 4; ++r) {
                    int pr = tr + lr0 + r;
                    if (pr < n) {
                        float val;
                        if (pr == pc) {
                            val = 1.0f;   // exact: dist(i,i) == 0
                        } else {
                            float d2 = s_sq[lr0 + r] + sb - 2.0f * av[r];
                            d2 = fmaxf(d2, 0.f);
                            val = fmaxf(1.0f - sqrtf(d2), 0.f);
                        }
                        local += val;
                    }
                }
            }
        }
        if (!diag) local *= 2.f;
#pragma unroll
        for (int s = 32; s > 0; s >>= 1) local += __shfl_xor(local, s);
        if (lane == 0) atomicAdd(&s_ps[dom], local);   // LDS atomic, uncontended
        __syncthreads();   // LDS reuse fence (only matters if block gets 2 tiles)
    }

    __syncthreads();
    if (t < NDOM) part[blockIdx.x * NDOM + t] = s_ps[t];  // private slot store
}

// -------------------------------------------------------------- finalize ----
__global__ __launch_bounds__(256) void k_final(
    const float* __restrict__ part, const int* __restrict__ dom_off,
    float* __restrict__ out) {
    __shared__ float red[8][32];
    int t = threadIdx.x;
    int d = t & 7, ch = t >> 3;           // 32 chunks x 8 domains
    float s = 0.f;
    for (int b = ch; b < GGRID; b += 32) s += part[b * NDOM + d];
    red[d][ch] = s;
    __syncthreads();
    if (t == 0) {
        float acc = 0.f;
        int v = 0;
        for (int dd = 0; dd < NDOM; ++dd) {
            int n = dom_off[dd + 1] - dom_off[dd];
            if (n > 1) {
                float ps = 0.f;
                for (int c = 0; c < 32; ++c) ps += red[dd][c];
                acc += ps / ((float)n * (float)n);
                ++v;
            }
        }
        out[0] = (v > 0) ? acc / (float)v : 0.f;
    }
}

// ---------------------------------------------------------------- launch ----
extern "C" void kernel_launch(void* const* d_in, const int* in_sizes, int n_in,
                              void* d_out, int out_size, void* d_ws, size_t ws_size,
                              hipStream_t stream) {
    const float* F = (const float*)d_in[0];
    const int* labels = (const int*)d_in[1];
    int B = in_sizes[1];                 // 4096

    char* ws = (char*)d_ws;
    unsigned char* Fb = (unsigned char*)ws;
    float* sq = (float*)(ws + (size_t)BMAX * KDIM);
    int* perm = (int*)(ws + (size_t)BMAX * KDIM + BMAX * 4);
    int* dom_off = (int*)(ws + (size_t)BMAX * KDIM + BMAX * 8);
    float* part = (float*)(ws + (size_t)BMAX * KDIM + BMAX * 8 + 256);

    int ncv = (B + 15) / 16;
    k_prep<<<ncv + 1, 256, 0, stream>>>(F, labels, B, Fb, sq, perm, dom_off);
    // PROBE: k_gram launched twice (idempotent — part fully overwritten each
    // run). Total-time delta vs R9 measures gram's true marginal cost, which
    // the fill-dominated top-5 profile cannot show.
    k_gram<<<GGRID, 256, 0, stream>>>(Fb, sq, perm, dom_off, part);
    k_gram<<<GGRID, 256, 0, stream>>>(Fb, sq, perm, dom_off, part);
    k_final<<<1, 256, 0, stream>>>(part, dom_off, (float*)d_out);
}

// Round 11
// 104.977 us; speedup vs baseline: 1.0927x; 1.0927x over previous
//
#include <hip/hip_runtime.h>

#define NDOM 8
#define TT   64      // logical tile dim (64x64 upper-triangle tiles)
#define KDIM 1024    // feature dim (harness-fixed)
#define KH   512     // K-half per phase-1 block
#define PSTR 1040    // LDS byte stride per ROW-PAIR (2x512B rows + 16B pad)
#define BMAX 4096    // batch (harness-fixed)
#define GGRID 512

typedef float f32x4 __attribute__((ext_vector_type(4)));

__device__ inline void gload16(const void* g, void* l) {
    __builtin_amdgcn_global_load_lds(
        (const __attribute__((address_space(1))) unsigned int*)g,
        (__attribute__((address_space(3))) unsigned int*)l, 16, 0, 0);
}

// Shared tile-table build + triangular decode (identical math to R9).
__device__ inline void build_tables(const int* dom_off, int* s_offs, int* s_ts) {
    int T = 0;
    for (int d = 0; d < NDOM; ++d) {
        int o0 = dom_off[d], o1 = dom_off[d + 1];
        s_offs[d] = o0;
        s_ts[d] = T;
        int n = o1 - o0;
        int nt = (n + TT - 1) / TT;
        T += nt * (nt + 1) / 2;
    }
    s_offs[NDOM] = dom_off[NDOM];
    s_ts[NDOM] = T;
}

__device__ inline void decode_tile(const int* s_offs, const int* s_ts, int tile,
                                   int& off, int& n, int& tr, int& tc,
                                   int& dom, bool& diag) {
    dom = 0;
    while (tile >= s_ts[dom + 1]) ++dom;
    off = s_offs[dom];
    n = s_offs[dom + 1] - off;
    int nt = (n + TT - 1) / TT;
    int rel = tile - s_ts[dom];
    int ty = 0, rem = rel;
    while (rem >= nt - ty) { rem -= nt - ty; ++ty; }
    int tx = ty + rem;
    tr = ty * TT; tc = tx * TT;
    diag = (ty == tx);
}

// ------------------------------------------------------------------ prep ----
// Block 0: label bucketing (ballot/popc) -> perm, dom_off; zero bar.
// Blocks 1..: fp32 -> fp8(e4m3) convert in ORIGINAL order (16 rows/block).
__global__ __launch_bounds__(256) void k_prep(
    const float* __restrict__ F, const int* __restrict__ labels, int B,
    unsigned char* __restrict__ Fb, float* __restrict__ sq,
    int* __restrict__ perm, int* __restrict__ dom_off, unsigned* __restrict__ bar) {
    const int t = threadIdx.x, lane = t & 63, wv = t >> 6;

    if (blockIdx.x == 0) {
        __shared__ int lab[BMAX];
        __shared__ unsigned wcnt[4][NDOM];
        for (int i = t; i < BMAX; i += 256) lab[i] = (i < B) ? labels[i] : -1;
        __syncthreads();

        int nch = (B + 63) >> 6;
        int cpw = (nch + 3) >> 2;
        int c0 = wv * cpw, c1 = min(c0 + cpw, nch);
        unsigned long long below = (1ull << lane) - 1ull;

        unsigned cnt[NDOM];
#pragma unroll
        for (int d = 0; d < NDOM; ++d) cnt[d] = 0;
        for (int c = c0; c < c1; ++c) {
            int d = lab[c * 64 + lane];
#pragma unroll
            for (int dd = 0; dd < NDOM; ++dd)
                cnt[dd] += (unsigned)__popcll(__ballot(d == dd));
        }
        if (lane == 0)
#pragma unroll
            for (int dd = 0; dd < NDOM; ++dd) wcnt[wv][dd] = cnt[dd];
        __syncthreads();

        unsigned offs[NDOM + 1];
        offs[0] = 0;
#pragma unroll
        for (int dd = 0; dd < NDOM; ++dd)
            offs[dd + 1] = offs[dd] + wcnt[0][dd] + wcnt[1][dd] + wcnt[2][dd] + wcnt[3][dd];
        if (t <= NDOM) dom_off[t] = (int)offs[t];
        if (t == 0) { bar[0] = 0u; bar[1] = 0u; }

        unsigned run[NDOM];
#pragma unroll
        for (int dd = 0; dd < NDOM; ++dd) {
            unsigned base = offs[dd];
            for (int w = 0; w < 4; ++w)
                if (w < wv) base += wcnt[w][dd];
            run[dd] = base;
        }
        for (int c = c0; c < c1; ++c) {
            int i = c * 64 + lane;
            int d = lab[i];
            int pos = -1;
#pragma unroll
            for (int dd = 0; dd < NDOM; ++dd) {
                unsigned long long m = __ballot(d == dd);
                if (d == dd) pos = (int)run[dd] + __popcll(m & below);
                run[dd] += (unsigned)__popcll(m);
            }
            if (i < B) perm[pos] = i;
        }
        return;
    }

    int i0 = (int)(blockIdx.x - 1) * 16;
    for (int j = wv; j < 16; j += 4) {
        int row = i0 + j;
        if (row >= B) break;
        const float4* srow = (const float4*)(F + (size_t)row * KDIM);
        int* drow = (int*)(Fb + (size_t)row * KDIM);
        float ss = 0.f;
#pragma unroll
        for (int it = 0; it < 4; ++it) {
            float4 v = srow[it * 64 + lane];
            ss += v.x * v.x + v.y * v.y + v.z * v.z + v.w * v.w;
            int p = __builtin_amdgcn_cvt_pk_fp8_f32(v.x, v.y, 0, false);
            p = __builtin_amdgcn_cvt_pk_fp8_f32(v.z, v.w, p, true);
            drow[it * 64 + lane] = p;
        }
#pragma unroll
        for (int s = 32; s > 0; s >>= 1) ss += __shfl_xor(ss, s);
        if (lane == 0) sq[row] = ss;
    }
}

// ---------------------------------------------------------------- phase1 ----
// One block per (tile, K-half): stage 64(+64) rows x 512B (row-PAIRS packed
// 1024B contiguous per global_load_lds, pair-stride 1040B -> <=2-way banks),
// 16 ks of fp8 MFMA, dump raw partial accumulators (same lane layout the
// phase-2 reader uses -> no transpose). 64KB LDS -> 2 blocks/CU overlap.
__global__ __launch_bounds__(256) void k_phase1(
    const unsigned char* __restrict__ Fb, const int* __restrict__ perm,
    const int* __restrict__ dom_off, float* __restrict__ pacc) {
    __shared__ __align__(16) unsigned char lA[32 * PSTR];  // 32 pairs = 64 rows
    __shared__ __align__(16) unsigned char lB[32 * PSTR];
    __shared__ int s_p[128];
    __shared__ int s_offs[NDOM + 1], s_ts[NDOM + 1];

    const int t = threadIdx.x, lane = t & 63, wv = t >> 6;
    const int m16 = lane & 15, quad = lane >> 4;
    const int wm = (wv & 1) * 32, wn = (wv >> 1) * 32;

    if (t == 0) build_tables(dom_off, s_offs, s_ts);
    __syncthreads();
    const int T = s_ts[NDOM];

    for (int half = blockIdx.x; half < 2 * T; half += gridDim.x) {
        int tile = half >> 1, h = half & 1;
        int off, n, tr, tc, dom;
        bool diag;
        decode_tile(s_offs, s_ts, tile, off, n, tr, tc, dom, diag);

        if (t < 128) {
            int r = (t < 64) ? min(tr + t, n - 1) : min(tc + (t - 64), n - 1);
            s_p[t] = perm[off + r];
        }
        __syncthreads();

        // stage: 1 instr covers a row-PAIR (lanes 0-31 row 2p, 32-63 row 2p+1)
#pragma unroll
        for (int j = 0; j < 8; ++j) {
            int pair = wv * 8 + j;
            int rsel = pair * 2 + (lane >> 5);
            const unsigned char* ga =
                Fb + (size_t)s_p[rsel] * KDIM + h * KH + (lane & 31) * 16;
            gload16(ga, lA + pair * PSTR);
            if (!diag) {
                const unsigned char* gb =
                    Fb + (size_t)s_p[64 + rsel] * KDIM + h * KH + (lane & 31) * 16;
                gload16(gb, lB + pair * PSTR);
            }
        }
        __syncthreads();   // single vmcnt drain per half

        const unsigned char* Bb = diag ? lA : lB;
        int rA0 = wm + m16, rA1 = wm + 16 + m16;
        int rB0 = wn + m16, rB1 = wn + 16 + m16;
        const unsigned char* pa0 = lA + (rA0 >> 1) * PSTR + (rA0 & 1) * KH + quad * 8;
        const unsigned char* pa1 = lA + (rA1 >> 1) * PSTR + (rA1 & 1) * KH + quad * 8;
        const unsigned char* pb0 = Bb + (rB0 >> 1) * PSTR + (rB0 & 1) * KH + quad * 8;
        const unsigned char* pb1 = Bb + (rB1 >> 1) * PSTR + (rB1 & 1) * KH + quad * 8;
        f32x4 a00 = (f32x4){0.f, 0.f, 0.f, 0.f};
        f32x4 a01 = (f32x4){0.f, 0.f, 0.f, 0.f};
        f32x4 a10 = (f32x4){0.f, 0.f, 0.f, 0.f};
        f32x4 a11 = (f32x4){0.f, 0.f, 0.f, 0.f};
#pragma unroll
        for (int ks = 0; ks < 16; ++ks) {
            long av0 = *(const long*)(pa0 + ks * 32);
            long av1 = *(const long*)(pa1 + ks * 32);
            long bv0 = *(const long*)(pb0 + ks * 32);
            long bv1 = *(const long*)(pb1 + ks * 32);
            a00 = __builtin_amdgcn_mfma_f32_16x16x32_fp8_fp8(av0, bv0, a00, 0, 0, 0);
            a01 = __builtin_amdgcn_mfma_f32_16x16x32_fp8_fp8(av0, bv1, a01, 0, 0, 0);
            a10 = __builtin_amdgcn_mfma_f32_16x16x32_fp8_fp8(av1, bv0, a10, 0, 0, 0);
            a11 = __builtin_amdgcn_mfma_f32_16x16x32_fp8_fp8(av1, bv1, a11, 0, 0, 0);
        }

        // dump raw partials: [half][wv][lane][4xf32x4] -- 16KB per half
        f32x4* dst = (f32x4*)pacc + (size_t)half * 1024 + wv * 256 + lane * 4;
        dst[0] = a00; dst[1] = a01; dst[2] = a10; dst[3] = a11;
        __syncthreads();   // LDS reuse fence before next half
    }
}

// ---------------------------------------------------------------- phase2 ----
// One block per tile: sum the two K-half partials (same lane layout), run the
// R9-proven epilogue, export block-private sums, last-arriving block finalizes.
__global__ __launch_bounds__(256) void k_phase2(
    const float* __restrict__ pacc, const float* __restrict__ sq,
    const int* __restrict__ perm, const int* __restrict__ dom_off,
    float* __restrict__ part, unsigned* __restrict__ bar,
    float* __restrict__ out) {
    __shared__ float s_sq[128];
    __shared__ int s_offs[NDOM + 1], s_ts[NDOM + 1];
    __shared__ float s_ps[NDOM];
    __shared__ float red[NDOM][33];
    __shared__ unsigned s_last;

    const int t = threadIdx.x, lane = t & 63, wv = t >> 6;
    const int m16 = lane & 15, quad = lane >> 4;
    const int wm = (wv & 1) * 32, wn = (wv >> 1) * 32;

    if (t == 0) build_tables(dom_off, s_offs, s_ts);
    if (t < NDOM) s_ps[t] = 0.f;
    __syncthreads();
    const int T = s_ts[NDOM];

    for (int tile = blockIdx.x; tile < T; tile += gridDim.x) {
        int off, n, tr, tc, dom;
        bool diag;
        decode_tile(s_offs, s_ts, tile, off, n, tr, tc, dom, diag);

        if (t < 128) {
            int r = (t < 64) ? min(tr + t, n - 1) : min(tc + (t - 64), n - 1);
            s_sq[t] = sq[perm[off + r]];
        }
        __syncthreads();

        const f32x4* p0 = (const f32x4*)pacc + (size_t)(tile * 2) * 1024 + wv * 256 + lane * 4;
        const f32x4* p1 = p0 + 1024;
        f32x4 a00 = p0[0] + p1[0];
        f32x4 a01 = p0[1] + p1[1];
        f32x4 a10 = p0[2] + p1[2];
        f32x4 a11 = p0[3] + p1[3];

        float local = 0.f;
#pragma unroll
        for (int im = 0; im < 2; ++im) {
            int lr0 = wm + im * 16 + quad * 4;
#pragma unroll
            for (int in = 0; in < 2; ++in) {
                f32x4 av = (im == 0) ? ((in == 0) ? a00 : a01)
                                     : ((in == 0) ? a10 : a11);
                int lc = wn + in * 16 + m16;
                int pc = tc + lc;
                if (pc >= n) continue;
                float sb = s_sq[64 + lc];
#pragma unroll
                for (int r = 0; r < 4; ++r) {
                    int pr = tr + lr0 + r;
                    if (pr < n) {
                        float val;
                        if (pr == pc) {
                            val = 1.0f;   // exact: dist(i,i) == 0
                        } else {
                            float d2 = s_sq[lr0 + r] + sb - 2.0f * av[r];
                            d2 = fmaxf(d2, 0.f);
                            val = fmaxf(1.0f - sqrtf(d2), 0.f);
                        }
                        local += val;
                    }
                }
            }
        }
        if (!diag) local *= 2.f;
#pragma unroll
        for (int s = 32; s > 0; s >>= 1) local += __shfl_xor(local, s);
        if (lane == 0) atomicAdd(&s_ps[dom], local);   // LDS atomic, uncontended
        __syncthreads();   // s_sq reuse fence
    }

    __syncthreads();
    if (t < NDOM) part[blockIdx.x * NDOM + t] = s_ps[t];
    __syncthreads();
    if (t == 0) {
        __threadfence();                  // release part stores
        unsigned old = atomicAdd(&bar[1], 1u);
        s_last = (old == (unsigned)gridDim.x - 1) ? 1u : 0u;
    }
    __syncthreads();
    if (s_last) {
        if (t == 0) __threadfence();      // acquire
        __syncthreads();
        int d = t & 7, ch = t >> 3;       // 32 chunks x 8 domains
        float s = 0.f;
        for (int b = ch; b < GGRID; b += 32)
            s += __hip_atomic_load(&part[b * NDOM + d], __ATOMIC_RELAXED,
                                   __HIP_MEMORY_SCOPE_AGENT);
        red[d][ch] = s;
        __syncthreads();
        if (t == 0) {
            float acc = 0.f;
            int v = 0;
            for (int dd = 0; dd < NDOM; ++dd) {
                int n = s_offs[dd + 1] - s_offs[dd];
                if (n > 1) {
                    float ps = 0.f;
                    for (int c = 0; c < 32; ++c) ps += red[dd][c];
                    acc += ps / ((float)n * (float)n);
                    ++v;
                }
            }
            out[0] = (v > 0) ? acc / (float)v : 0.f;
        }
    }
}

// ---------------------------------------------------------------- launch ----
extern "C" void kernel_launch(void* const* d_in, const int* in_sizes, int n_in,
                              void* d_out, int out_size, void* d_ws, size_t ws_size,
                              hipStream_t stream) {
    const float* F = (const float*)d_in[0];
    const int* labels = (const int*)d_in[1];
    int B = in_sizes[1];                 // 4096

    char* ws = (char*)d_ws;
    unsigned char* Fb = (unsigned char*)ws;                  // 4 MB
    float* sq = (float*)(ws + 0x400000);                     // 16 KB
    int* perm = (int*)(ws + 0x404000);                       // 16 KB
    int* dom_off = (int*)(ws + 0x408000);
    unsigned* bar = (unsigned*)(ws + 0x408100);
    float* part = (float*)(ws + 0x409000);                   // 16 KB
    float* pacc = (float*)(ws + 0x500000);                   // up to ~66 MB

    int ncv = (B + 15) / 16;
    k_prep<<<ncv + 1, 256, 0, stream>>>(F, labels, B, Fb, sq, perm, dom_off, bar);
    k_phase1<<<GGRID, 256, 0, stream>>>(Fb, perm, dom_off, pacc);
    k_phase2<<<GGRID, 256, 0, stream>>>(pacc, sq, perm, dom_off, part, bar, (float*)d_out);
}